// Round 8
// baseline (100.937 us; speedup 1.0000x reference)
//
#include <hip/hip_runtime.h>
#include <math.h>

#define NLAT 360
#define NLON 720
#define LMAX 360
#define MMAX 361
#define KPAD 368    // stage-1 col space per (b,c): 32*368 = 11776 cols
#define KP2  384    // XR k-stride (stage-2 K padding, multiple of 32)
#define FT_COLS 736 // DFT K padded to multiple of 32
#define FT_ROWS_PAD 384
#define NJ   32     // 32 (b,c) pairs

typedef __attribute__((ext_vector_type(4))) float f32x4;
typedef __attribute__((ext_vector_type(8))) short bf16x8;
typedef __attribute__((ext_vector_type(4))) short bf16x4;

__device__ __forceinline__ short f2bf(float f) {
    union { float f; unsigned u; } v; v.f = f;
    unsigned r = (v.u + 0x7FFFu + ((v.u >> 16) & 1u)) >> 16;
    return (short)r;
}

// ---------------- zero-fill ----------------
__global__ __launch_bounds__(256) void zero_kernel(unsigned* __restrict__ p, long nwords) {
    long i = (long)blockIdx.x * 256 + threadIdx.x;
    const long stride = (long)gridDim.x * 256;
    for (; i < nwords; i += stride) p[i] = 0u;
}

// ---------------- kernel 0: bf16 cosine-DFT matrix FT[m][n] ----------------
__global__ __launch_bounds__(256) void fill_ft_kernel(short* __restrict__ FT) {
    int idx = blockIdx.x * 256 + threadIdx.x;
    const int total = MMAX * NLON;
    if (idx >= total) return;
    int n = idx % NLON;
    int m = idx / NLON;
    int t = (m * n) % NLON;                 // exact integer angle reduction
    float s, c;
    sincospif((float)t / 360.0f, &s, &c);   // cos(2pi*t/720)
    const float scale = 6.283185307179586f / 720.0f;
    FT[m * FT_COLS + n] = f2bf(scale * c);
}

// ---------------- stage 1: C[m][bck] = sum_n FT[m][n] * x[bck][n] ----------
// writes XR[((m-m0)*32 + bc)*KP2 + klat] bf16   (validated rounds 5-7)
__global__ __launch_bounds__(256) void stage1_kernel(const float* __restrict__ x,
                                                     const short* __restrict__ FT,
                                                     short* __restrict__ XR,
                                                     int m0, int cm) {
    __shared__ __align__(16) short Al[64 * 40];
    __shared__ __align__(16) short Bl[64 * 40];
    const int tid  = threadIdx.x;
    const int col0 = blockIdx.x * 64;
    const int row0 = m0 + blockIdx.y * 64;
    const int m_hi = (m0 + cm < MMAX) ? (m0 + cm) : MMAX;
    const int wid  = tid >> 6;
    const int lane = tid & 63;
    const int si = tid >> 2;
    const int sc = tid & 3;

    const int bcol = col0 + si;
    const int bc   = bcol / KPAD;
    const int klat = bcol - bc * KPAD;
    const bool rowvalid = (klat < NLAT);
    const float* xrow = x + (size_t)(bc * NLAT + klat) * NLON;

    const int aRow   = wid * 16 + (lane & 15);
    const int aChunk = (lane >> 4) * 8;
    const int colL   = lane & 15;

    f32x4 acc[4] = {{0,0,0,0},{0,0,0,0},{0,0,0,0},{0,0,0,0}};

    for (int k0 = 0; k0 < FT_COLS; k0 += 32) {
        __syncthreads();
        *(bf16x8*)&Al[si * 40 + sc * 8] =
            *(const bf16x8*)&FT[(size_t)(row0 + si) * FT_COLS + k0 + sc * 8];
        {
            const int n = k0 + sc * 8;
            f32x4 va = {0,0,0,0}, vb = {0,0,0,0};
            if (rowvalid && n < NLON) {
                va = *(const f32x4*)&xrow[n];
                vb = *(const f32x4*)&xrow[n + 4];
            }
            bf16x4 wa, wb;
            #pragma unroll
            for (int e = 0; e < 4; ++e) { wa[e] = f2bf(va[e]); wb[e] = f2bf(vb[e]); }
            *(bf16x4*)&Bl[si * 40 + sc * 8]     = wa;
            *(bf16x4*)&Bl[si * 40 + sc * 8 + 4] = wb;
        }
        __syncthreads();
        bf16x8 af = *(const bf16x8*)&Al[aRow * 40 + aChunk];
        #pragma unroll
        for (int f = 0; f < 4; ++f) {
            bf16x8 bfrag = *(const bf16x8*)&Bl[(f * 16 + colL) * 40 + aChunk];
            acc[f] = __builtin_amdgcn_mfma_f32_16x16x32_bf16(af, bfrag, acc[f], 0, 0, 0);
        }
    }

    const int mbase = row0 + wid * 16 + ((lane >> 4) << 2);
    #pragma unroll
    for (int f = 0; f < 4; ++f) {
        const int bck = col0 + f * 16 + colL;
        const int obc = bck / KPAD;
        const int okl = bck - obc * KPAD;
        #pragma unroll
        for (int i = 0; i < 4; ++i) {
            const int m = mbase + i;
            if (m < m_hi) {
                XR[(size_t)((m - m0) * NJ + obc) * KP2 + okl] = f2bf(acc[f][i]);
            }
        }
    }
}

// ---------------- stage 2: triangle grid, bc-split, reg double-buffer ------
// Grid: x = (ltile 0..11)*2 + bchalf, y = m-tile (8 m). Block 512 thr = 8 waves.
// Wave = (l-half) x (m-pair): 16l x 16bc x 2m, K = 12 steps of 32.
// Blocks fully below the W zero-triangle exit immediately (out pre-zeroed).
#define S2_LOAD(kk, XA0, XA1, XB0, XB1, YB0, YB1)                               \
  {                                                                             \
    const bool kv = ((kk) + kg) < NLAT;                                         \
    f32x4 z4 = {0,0,0,0};                                                       \
    bf16x8 z8 = {0,0,0,0,0,0,0,0};                                              \
    XA0 = z4; XA1 = z4; XB0 = z4; XB1 = z4;                                     \
    if (w0) {                                                                   \
      if (lAv && kv && lA >= mA0) {                                             \
        XA0 = *(const f32x4*)(wp0 + (kk));                                      \
        XA1 = *(const f32x4*)(wp0 + (kk) + 4);                                  \
      }                                                                         \
      YB0 = *(const bf16x8*)(xp0 + (kk));                                       \
    } else { YB0 = z8; }                                                        \
    if (w1) {                                                                   \
      if (lAv && kv && lA >= mA1) {                                             \
        XB0 = *(const f32x4*)(wp1 + (kk));                                      \
        XB1 = *(const f32x4*)(wp1 + (kk) + 4);                                  \
      }                                                                         \
      YB1 = *(const bf16x8*)(xp1 + (kk));                                       \
    } else { YB1 = z8; }                                                        \
  }

#define S2_COMP(XA0, XA1, XB0, XB1, YB0, YB1)                                   \
  {                                                                             \
    bf16x8 af0, af1;                                                            \
    _Pragma("unroll")                                                           \
    for (int e = 0; e < 4; ++e) {                                               \
      af0[e] = f2bf(XA0[e]); af0[e + 4] = f2bf(XA1[e]);                         \
      af1[e] = f2bf(XB0[e]); af1[e + 4] = f2bf(XB1[e]);                         \
    }                                                                           \
    acc0 = __builtin_amdgcn_mfma_f32_16x16x32_bf16(af0, YB0, acc0, 0, 0, 0);    \
    acc1 = __builtin_amdgcn_mfma_f32_16x16x32_bf16(af1, YB1, acc1, 0, 0, 0);    \
  }

__global__ __launch_bounds__(512) void stage2_kernel(const float* __restrict__ W,
                                                     const short* __restrict__ XR,
                                                     float* __restrict__ out,
                                                     int m0, int m_hi) {
    const int ltile = blockIdx.x >> 1;
    const int bch   = blockIdx.x & 1;
    const int mtile = blockIdx.y;
    if (ltile * 32 + 31 < m0 + mtile * 8) return;   // fully in zero triangle

    const int tid  = threadIdx.x;
    const int wav  = tid >> 6;           // 0..7
    const int lane = tid & 63;
    const int l0   = ltile * 32 + (wav & 1) * 16;
    const int mA0  = m0 + mtile * 8 + (wav >> 1) * 2;
    const int mA1  = mA0 + 1;
    const int r    = lane & 15;
    const int kg   = (lane >> 4) * 8;
    const int lA   = l0 + r;
    const bool lAv = (lA < LMAX);
    const int lmaxw = l0 + 15;
    const bool w0  = (mA0 < m_hi) && (lmaxw >= mA0);
    const bool w1  = (mA1 < m_hi) && (lmaxw >= mA1);
    const int bc0  = bch * 16;

    f32x4 acc0 = {0,0,0,0}, acc1 = {0,0,0,0};

    if (w0 || w1) {
        const float* wp0 = W + ((size_t)mA0 * LMAX + lA) * NLAT + kg;
        const float* wp1 = W + ((size_t)mA1 * LMAX + lA) * NLAT + kg;
        const short* xp0 = XR + ((size_t)(mA0 - m0) * NJ + bc0 + r) * KP2 + kg;
        const short* xp1 = XR + ((size_t)(mA1 - m0) * NJ + bc0 + r) * KP2 + kg;

        f32x4 A0, A1, A2, A3;    // cur A (m0 lo/hi, m1 lo/hi)
        bf16x8 B0, B1;           // cur B (m0, m1)
        f32x4 P0, P1, P2, P3;    // prefetch A
        bf16x8 Q0, Q1;           // prefetch B

        S2_LOAD(0, A0, A1, A2, A3, B0, B1);
        #pragma unroll
        for (int t = 0; t < 12; ++t) {
            const int kn = (t + 1) * 32;
            if ((t & 1) == 0) {
                if (t < 11) S2_LOAD(kn, P0, P1, P2, P3, Q0, Q1);
                S2_COMP(A0, A1, A2, A3, B0, B1);
            } else {
                if (t < 11) S2_LOAD(kn, A0, A1, A2, A3, B0, B1);
                S2_COMP(P0, P1, P2, P3, Q0, Q1);
            }
        }
    }

    // epilogue: row = l0+(lane>>4)*4+i (l), col = bc0+r (bc); m-pair stores
    const int rowg = (lane >> 4) * 4;
    #pragma unroll
    for (int i = 0; i < 4; ++i) {
        const int l = l0 + rowg + i;
        if (l < LMAX) {
            float* op = out + ((size_t)(bc0 + r) * LMAX + l) * MMAX + mA0;
            if (mA0 < MMAX) op[0] = acc0[i];
            if (mA1 < MMAX) op[1] = acc1[i];
        }
    }
}

extern "C" void kernel_launch(void* const* d_in, const int* in_sizes, int n_in,
                              void* d_out, int out_size, void* d_ws, size_t ws_size,
                              hipStream_t stream) {
    const float* x = (const float*)d_in[0];
    const float* w = (const float*)d_in[1];
    float* out = (float*)d_out;

    const size_t XR_OFF = (size_t)FT_ROWS_PAD * FT_COLS * 2;  // 565,248 B
    const size_t PER_M  = (size_t)NJ * KP2 * 2;               // 24,576 B per mode
    long cm = 0;
    if (d_ws != nullptr && ws_size > XR_OFF + PER_M) cm = (long)((ws_size - XR_OFF) / PER_M);
    if (cm > MMAX) cm = MMAX;
    if (cm < 1) return;  // ws proven >= 10.05 MB in round 5; unreachable

    short* FT = (short*)d_ws;
    short* XR = (short*)((char*)d_ws + XR_OFF);
    const long zero_words = (long)((XR_OFF + (size_t)cm * PER_M) / 4);
    zero_kernel<<<2048, 256, 0, stream>>>((unsigned*)d_ws, zero_words);
    zero_kernel<<<2048, 256, 0, stream>>>((unsigned*)out, (long)out_size);
    fill_ft_kernel<<<(MMAX * NLON + 255) / 256, 256, 0, stream>>>(FT);
    for (int m0 = 0; m0 < MMAX; m0 += (int)cm) {
        const int cmx = ((int)cm < MMAX - m0) ? (int)cm : (MMAX - m0);
        const int gy1 = (cmx + 63) / 64;
        stage1_kernel<<<dim3(184, gy1), 256, 0, stream>>>(x, FT, XR, m0, cmx);
        const int gy2 = (cmx + 7) / 8;
        stage2_kernel<<<dim3(24, gy2), 512, 0, stream>>>(w, XR, out, m0, m0 + cmx);
    }
}